// Round 9
// baseline (21400.735 us; speedup 1.0000x reference)
//
#include <hip/hip_runtime.h>
#include <hip/hip_bf16.h>
#include <math.h>

// Problem dims
#define T_N   4096
#define IN_N  1024
#define H_N   2048
#define OUT_N 1024

// Recurrence: KD blocks per direction, RPB rows each, 16 waves x 2 rows.
#define KD   64
#define RPB  32
#define RTH  1024

#define SENT 0xFFFFFFFFu   // -NaN; tanh output (finite, [-1,1]) never equals it

// Workspace byte offsets (total 98 MiB, well under proven ~128 MiB)
#define XW_F_OFF 0ull
#define XW_B_OFF 33554432ull          // 32 MiB
#define HF_OFF   67108864ull          // bf16 [T][H] = 16 MiB
#define HB_OFF   83886080ull          // 80 MiB
#define IB_F_OFF 100663296ull         // 96 MiB: 64 blk x 2 par x 1024 ull = 1 MiB
#define IB_B_OFF 101711872ull         // 97 MiB
// end = 98 MiB

static __device__ __forceinline__ unsigned short f2bf(float f) {
  unsigned x = __float_as_uint(f);
  return (unsigned short)((x + 0x7FFFu + ((x >> 16) & 1u)) >> 16);
}
static __device__ __forceinline__ float bf2f(unsigned short u) {
  return __uint_as_float(((unsigned)u) << 16);
}

// Fill both inbox regions (2 MiB = 262144 ull) with sentinel each call.
__global__ __launch_bounds__(1024) void inbox_fill_kernel(unsigned long long* __restrict__ p) {
  p[blockIdx.x * 1024ull + threadIdx.x] = 0xFFFFFFFFFFFFFFFFull;
}

// ---------------------------------------------------------------------------
// Tiled fp32 NT GEMM: xw = x@Wx^T + bh. 64x64 tile, BK=16, 256 thr, 4x4/thr.
// ---------------------------------------------------------------------------
__global__ __launch_bounds__(256) void gemm_xw_kernel(
    const float* __restrict__ x,
    const float* __restrict__ Wxf, const float* __restrict__ bhf,
    const float* __restrict__ Wxb, const float* __restrict__ bhb,
    float* __restrict__ xwf, float* __restrict__ xwb)
{
  const int dir = blockIdx.z;
  const float* __restrict__ B    = dir ? Wxb : Wxf;
  const float* __restrict__ bias = dir ? bhb : bhf;
  float* __restrict__ C          = dir ? xwb : xwf;
  const int bm0 = blockIdx.y * 64;   // T dim
  const int bn0 = blockIdx.x * 64;   // H dim

  __shared__ float As[16][65];
  __shared__ float Bs[16][65];
  const int tid  = threadIdx.x;
  const int ty   = tid >> 4, tx = tid & 15;
  const int lrow = tid >> 2, lkq = (tid & 3) << 2;
  float acc[4][4] = {};

  for (int k0 = 0; k0 < IN_N; k0 += 16) {
    float4 a4 = *(const float4*)(x + (size_t)(bm0 + lrow) * IN_N + k0 + lkq);
    float4 b4 = *(const float4*)(B + (size_t)(bn0 + lrow) * IN_N + k0 + lkq);
    As[lkq + 0][lrow] = a4.x; As[lkq + 1][lrow] = a4.y;
    As[lkq + 2][lrow] = a4.z; As[lkq + 3][lrow] = a4.w;
    Bs[lkq + 0][lrow] = b4.x; Bs[lkq + 1][lrow] = b4.y;
    Bs[lkq + 2][lrow] = b4.z; Bs[lkq + 3][lrow] = b4.w;
    __syncthreads();
#pragma unroll
    for (int k = 0; k < 16; ++k) {
      float a[4], bv[4];
#pragma unroll
      for (int i = 0; i < 4; ++i) a[i] = As[k][ty * 4 + i];
#pragma unroll
      for (int j = 0; j < 4; ++j) bv[j] = Bs[k][tx * 4 + j];
#pragma unroll
      for (int i = 0; i < 4; ++i)
#pragma unroll
        for (int j = 0; j < 4; ++j) acc[i][j] = fmaf(a[i], bv[j], acc[i][j]);
    }
    __syncthreads();
  }
#pragma unroll
  for (int i = 0; i < 4; ++i) {
    float4 v;
    v.x = acc[i][0] + bias[bn0 + tx * 4 + 0];
    v.y = acc[i][1] + bias[bn0 + tx * 4 + 1];
    v.z = acc[i][2] + bias[bn0 + tx * 4 + 2];
    v.w = acc[i][3] + bias[bn0 + tx * 4 + 3];
    *(float4*)(C + (size_t)(bm0 + ty * 4 + i) * H_N + bn0 + tx * 4) = v;
  }
}

// ---------------------------------------------------------------------------
// Output GEMM: y = hf@Wyf^T + hb@Wyb^T + by. A (h histories) is bf16.
// ---------------------------------------------------------------------------
__global__ __launch_bounds__(256) void gemm_out_kernel(
    const unsigned short* __restrict__ hf, const unsigned short* __restrict__ hb,
    const float* __restrict__ Wyf, const float* __restrict__ Wyb,
    const float* __restrict__ by, float* __restrict__ y)
{
  const int bm0 = blockIdx.y * 64;   // T dim
  const int bn0 = blockIdx.x * 64;   // OUT dim
  __shared__ float As[16][65];
  __shared__ float Bs[16][65];
  const int tid  = threadIdx.x;
  const int ty   = tid >> 4, tx = tid & 15;
  const int lrow = tid >> 2, lkq = (tid & 3) << 2;
  float acc[4][4] = {};

#pragma unroll 1
  for (int pass = 0; pass < 2; ++pass) {
    const unsigned short* __restrict__ A = pass ? hb : hf;
    const float* __restrict__ B = pass ? Wyb : Wyf;
    for (int k0 = 0; k0 < H_N; k0 += 16) {
      ushort4 a4 = *(const ushort4*)(A + (size_t)(bm0 + lrow) * H_N + k0 + lkq);
      float4 b4  = *(const float4*)(B + (size_t)(bn0 + lrow) * H_N + k0 + lkq);
      As[lkq + 0][lrow] = bf2f(a4.x); As[lkq + 1][lrow] = bf2f(a4.y);
      As[lkq + 2][lrow] = bf2f(a4.z); As[lkq + 3][lrow] = bf2f(a4.w);
      Bs[lkq + 0][lrow] = b4.x; Bs[lkq + 1][lrow] = b4.y;
      Bs[lkq + 2][lrow] = b4.z; Bs[lkq + 3][lrow] = b4.w;
      __syncthreads();
#pragma unroll
      for (int k = 0; k < 16; ++k) {
        float a[4], bv[4];
#pragma unroll
        for (int i = 0; i < 4; ++i) a[i] = As[k][ty * 4 + i];
#pragma unroll
        for (int j = 0; j < 4; ++j) bv[j] = Bs[k][tx * 4 + j];
#pragma unroll
        for (int i = 0; i < 4; ++i)
#pragma unroll
          for (int j = 0; j < 4; ++j) acc[i][j] = fmaf(a[i], bv[j], acc[i][j]);
      }
      __syncthreads();
    }
  }
#pragma unroll
  for (int i = 0; i < 4; ++i) {
    float4 v;
    v.x = acc[i][0] + by[bn0 + tx * 4 + 0];
    v.y = acc[i][1] + by[bn0 + tx * 4 + 1];
    v.z = acc[i][2] + by[bn0 + tx * 4 + 2];
    v.w = acc[i][3] + by[bn0 + tx * 4 + 3];
    *(float4*)(y + (size_t)(bm0 + ty * 4 + i) * OUT_N + bn0 + tx * 4) = v;
  }
}

// ---------------------------------------------------------------------------
// Persistent bidirectional recurrence, v9 — PER-CONSUMER INBOX PUSH.
// 128 blocks x 1024 threads (16 waves x 2 rows), weights pinned in regs.
// Inbox layout (per dir, ull units): slot(c, par, q) = c*2048 + par*1024 + q,
// q = row-pair index (0..1023). h_t lives at parity t&1.
// Per step:
//   each thread sentinel-polls ITS OWN slot of parity pt&1 (poll == staging
//   load, one LLC RT on the critical path; 16 pollers/line, single block)
//   -> write 8B to LDS + reset slot to sentinel -> barrier (vmcnt(0) drains
//   resets) -> 64 FMA/lane + butterfly -> all lanes know both row sums ->
//   tanh -> lane0 plain-stores bf16 hist pair -> wave scatter-stores packed
//   8B to all 64 consumers' inboxes (ONE instruction, lane i -> consumer i)
//   -> barrier (WAR on hs).
// Race-freedom of reset vs rewrite: producers rewrite my inbox[par] only
// after polling h_t, which I scatter only after the barrier that drained my
// resets => reset globally visible before any rewrite. Zero HW fences.
// ---------------------------------------------------------------------------
__global__ __launch_bounds__(RTH, 4) void recurrent_kernel(
    const float* __restrict__ Whf, const float* __restrict__ Whb,
    const float* __restrict__ xwf, const float* __restrict__ xwb,
    unsigned short* __restrict__ hf, unsigned short* __restrict__ hb,
    unsigned long long* __restrict__ ibf, unsigned long long* __restrict__ ibb)
{
  const int b    = blockIdx.x;
  const bool fwd = (b < KD);
  const int bb   = fwd ? b : b - KD;
  const int rb   = bb * RPB;
  const float* __restrict__ Wh = fwd ? Whf : Whb;
  const float* __restrict__ xw = fwd ? xwf : xwb;
  unsigned short* __restrict__ hist   = fwd ? hf : hb;
  unsigned long long* __restrict__ ib = fwd ? ibf : ibb;

  const int w     = threadIdx.x >> 6;   // wave 0..15
  const int lane  = threadIdx.x & 63;
  const int jbase = lane << 2;          // 0..252
  const int r0    = rb + 2 * w;         // this wave's two rows
  const int q     = bb * 16 + w;        // producer row-pair slot index

  __shared__ __align__(16) float hs[H_N];   // 8 KB staged h_prev

  // One-time: weight slice into registers (64 VGPRs/lane), pinned.
  float4 wv[2][8];
#pragma unroll
  for (int qq = 0; qq < 2; ++qq)
#pragma unroll
    for (int k = 0; k < 8; ++k)
      wv[qq][k] = *(const float4*)(Wh + (size_t)(r0 + qq) * H_N + k * 256 + jbase);
#pragma unroll
  for (int qq = 0; qq < 2; ++qq)
#pragma unroll
    for (int k = 0; k < 8; ++k)
      asm volatile("" : "+v"(wv[qq][k].x), "+v"(wv[qq][k].y),
                        "+v"(wv[qq][k].z), "+v"(wv[qq][k].w));

  for (int s = 0; s < T_N; ++s) {
    const int t  = fwd ? s : (T_N - 1 - s);
    const int pt = fwd ? (t - 1) : (t + 1);
    const int wp = t & 1;                // parity this step's h is written to

    // xw for our two rows; lane0 loads, broadcast later (overlaps poll).
    float xwv0 = 0.f, xwv1 = 0.f;
    if (lane == 0) {
      xwv0 = xw[(size_t)t * H_N + r0 + 0];
      xwv1 = xw[(size_t)t * H_N + r0 + 1];
    }
    xwv0 = __shfl(xwv0, 0, 64);
    xwv1 = __shfl(xwv1, 0, 64);

    if (s > 0) {
      unsigned long long* slot =
          ib + (size_t)bb * 2048 + (size_t)(pt & 1) * 1024 + threadIdx.x;
      unsigned long long v;
      for (;;) {
        v = __hip_atomic_load(slot, __ATOMIC_RELAXED, __HIP_MEMORY_SCOPE_AGENT);
        if ((unsigned)v != SENT && (unsigned)(v >> 32) != SENT) break;
        __builtin_amdgcn_s_sleep(1);
      }
      ((unsigned long long*)hs)[threadIdx.x] = v;
      __hip_atomic_store(slot, 0xFFFFFFFFFFFFFFFFull, __ATOMIC_RELAXED,
                         __HIP_MEMORY_SCOPE_AGENT);   // reset for reuse
    } else {
      ((unsigned long long*)hs)[threadIdx.x] = 0ull;
    }
    __syncthreads();   // stage visible; ALL resets vmcnt-drained (pre-scatter)

    // LDS fragments: conflict-free ds_read_b128 (lane-consecutive 16B).
    float acc0 = 0.f, acc1 = 0.f;
#pragma unroll
    for (int k = 0; k < 8; ++k) {
      float4 h4 = *(const float4*)(hs + k * 256 + jbase);
      acc0 = fmaf(wv[0][k].x, h4.x, acc0);
      acc0 = fmaf(wv[0][k].y, h4.y, acc0);
      acc0 = fmaf(wv[0][k].z, h4.z, acc0);
      acc0 = fmaf(wv[0][k].w, h4.w, acc0);
      acc1 = fmaf(wv[1][k].x, h4.x, acc1);
      acc1 = fmaf(wv[1][k].y, h4.y, acc1);
      acc1 = fmaf(wv[1][k].z, h4.z, acc1);
      acc1 = fmaf(wv[1][k].w, h4.w, acc1);
    }
#pragma unroll
    for (int off = 32; off > 0; off >>= 1) {
      acc0 += __shfl_xor(acc0, off, 64);
      acc1 += __shfl_xor(acc1, off, 64);
    }
    // Every lane now holds both full row sums.
    float h0f = tanhf(acc0 + xwv0);
    float h1f = tanhf(acc1 + xwv1);

    if (lane == 0) {   // bf16 hist for the output GEMM (plain cached store)
      *(unsigned*)(hist + (size_t)t * H_N + r0) =
          (unsigned)f2bf(h0f) | ((unsigned)f2bf(h1f) << 16);
    }

    // Push to all 64 consumers: ONE scatter-store, lane i -> consumer i.
    unsigned long long pk =
        ((unsigned long long)__float_as_uint(h1f) << 32) | __float_as_uint(h0f);
    __hip_atomic_store(ib + (size_t)lane * 2048 + (size_t)wp * 1024 + q, pk,
                       __ATOMIC_RELAXED, __HIP_MEMORY_SCOPE_AGENT);

    __syncthreads();   // WAR: hs fully consumed before next step's restage
  }
}

extern "C" void kernel_launch(void* const* d_in, const int* in_sizes, int n_in,
                              void* d_out, int out_size, void* d_ws, size_t ws_size,
                              hipStream_t stream) {
  const float* x   = (const float*)d_in[0];
  const float* Wxf = (const float*)d_in[1];
  const float* Whf = (const float*)d_in[2];
  const float* bhf = (const float*)d_in[3];
  const float* Wxb = (const float*)d_in[4];
  const float* Whb = (const float*)d_in[5];
  const float* bhb = (const float*)d_in[6];
  const float* Wyf = (const float*)d_in[7];
  const float* Wyb = (const float*)d_in[8];
  const float* by  = (const float*)d_in[9];
  float* y = (float*)d_out;

  char* ws = (char*)d_ws;
  float* xwf = (float*)(ws + XW_F_OFF);
  float* xwb = (float*)(ws + XW_B_OFF);
  unsigned short* hf = (unsigned short*)(ws + HF_OFF);
  unsigned short* hb = (unsigned short*)(ws + HB_OFF);
  unsigned long long* ibf = (unsigned long long*)(ws + IB_F_OFF);
  unsigned long long* ibb = (unsigned long long*)(ws + IB_B_OFF);

  // Sentinel-fill both inboxes (2 MiB) every call — harness doesn't re-poison.
  hipLaunchKernelGGL(inbox_fill_kernel, dim3(256), dim3(1024), 0, stream, ibf);
  hipLaunchKernelGGL(gemm_xw_kernel, dim3(H_N / 64, T_N / 64, 2), dim3(256), 0, stream,
                     x, Wxf, bhf, Wxb, bhb, xwf, xwb);
  hipLaunchKernelGGL(recurrent_kernel, dim3(2 * KD), dim3(RTH), 0, stream,
                     Whf, Whb, xwf, xwb, hf, hb, ibf, ibb);
  hipLaunchKernelGGL(gemm_out_kernel, dim3(OUT_N / 64, T_N / 64), dim3(256), 0, stream,
                     hf, hb, Wyf, Wyb, by, y);
}

// Round 10
// 11222.579 us; speedup vs baseline: 1.9069x; 1.9069x over previous
//
#include <hip/hip_runtime.h>
#include <hip/hip_bf16.h>
#include <math.h>

// Problem dims
#define T_N   4096
#define IN_N  1024
#define H_N   2048
#define OUT_N 1024

// Recurrence (v5 core): KD blocks per direction, RPB rows each.
#define KD3  64
#define RPB3 32
#define RTH3 1024      // 16 waves, 2 rows per wave

// Workspace byte offsets (total 120 MiB + 512 B, under proven ~128 MiB)
#define XW_F_OFF 0ull                  // bf16 [T][H]  16 MiB
#define XW_B_OFF 16777216ull
#define HF_OFF   33554432ull           // fp32 [T][H]  32 MiB
#define HB_OFF   67108864ull
#define XBF_OFF  100663296ull          // bf16 x       8 MiB
#define WXF_OFF  109051904ull          // bf16 Wx_f    4 MiB
#define WXB_OFF  113246208ull
#define WYF_OFF  117440512ull          // bf16 Wy_f    4 MiB
#define WYB_OFF  121634816ull
#define PROG_OFF 125829120ull          // progf[64], progb[64]

typedef __attribute__((ext_vector_type(8))) short bf16x8;
typedef __attribute__((ext_vector_type(4))) float f32x4;

static __device__ __forceinline__ unsigned short f2bf(float f) {
  unsigned x = __float_as_uint(f);
  return (unsigned short)((x + 0x7FFFu + ((x >> 16) & 1u)) >> 16);
}
static __device__ __forceinline__ float bf2f(unsigned short u) {
  return __uint_as_float(((unsigned)u) << 16);
}

__global__ __launch_bounds__(128) void init_prog_kernel(unsigned* __restrict__ p) {
  p[threadIdx.x] = 0u;
}

// fp32 -> bf16 pack, vectorized.
__global__ __launch_bounds__(256) void cvt_kernel(const float4* __restrict__ src,
                                                  ushort4* __restrict__ dst, int n4) {
  for (int i = blockIdx.x * 256 + threadIdx.x; i < n4; i += gridDim.x * 256) {
    float4 v = src[i];
    dst[i] = make_ushort4(f2bf(v.x), f2bf(v.y), f2bf(v.z), f2bf(v.w));
  }
}

// ---------------------------------------------------------------------------
// MFMA bf16 NT GEMM #1: xw[dir] = x @ Wx[dir]^T + bh[dir], output bf16.
// 128x128 tile, 4 waves, 16x16x32 frags; LDS rows padded to 40 bf16 (80 B).
// ---------------------------------------------------------------------------
__global__ __launch_bounds__(256) void gemm_xw_mfma(
    const unsigned short* __restrict__ xbf,
    const unsigned short* __restrict__ Wf, const float* __restrict__ bhf,
    const unsigned short* __restrict__ Wb, const float* __restrict__ bhb,
    unsigned short* __restrict__ xwf, unsigned short* __restrict__ xwb)
{
  const int dir = blockIdx.z;
  const unsigned short* __restrict__ W = dir ? Wb : Wf;
  const float* __restrict__ bias = dir ? bhb : bhf;
  unsigned short* __restrict__ C = dir ? xwb : xwf;
  const int bm0 = blockIdx.y * 128;   // T rows
  const int bn0 = blockIdx.x * 128;   // H cols

  __shared__ unsigned short As[128 * 40];
  __shared__ unsigned short Bs[128 * 40];

  const int tid  = threadIdx.x;
  const int w    = tid >> 6, lane = tid & 63;
  const int wr   = w >> 1, wc = w & 1;
  const int fr   = lane & 15, fc = lane >> 4;

  f32x4 acc[4][4] = {};

  for (int k0 = 0; k0 < IN_N; k0 += 32) {
#pragma unroll
    for (int i = 0; i < 2; ++i) {
      int chunk = tid + i * 256;              // 512 chunks of 8 bf16
      int row = chunk >> 2, kk = (chunk & 3) * 8;
      uint4 av = *(const uint4*)(xbf + (size_t)(bm0 + row) * IN_N + k0 + kk);
      uint4 bv = *(const uint4*)(W   + (size_t)(bn0 + row) * IN_N + k0 + kk);
      *(uint4*)(As + row * 40 + kk) = av;
      *(uint4*)(Bs + row * 40 + kk) = bv;
    }
    __syncthreads();
    bf16x8 af[4], bfr[4];
#pragma unroll
    for (int i = 0; i < 4; ++i)
      af[i] = *(const bf16x8*)(As + (wr * 64 + i * 16 + fr) * 40 + fc * 8);
#pragma unroll
    for (int j = 0; j < 4; ++j)
      bfr[j] = *(const bf16x8*)(Bs + (wc * 64 + j * 16 + fr) * 40 + fc * 8);
#pragma unroll
    for (int i = 0; i < 4; ++i)
#pragma unroll
      for (int j = 0; j < 4; ++j)
        acc[i][j] = __builtin_amdgcn_mfma_f32_16x16x32_bf16(af[i], bfr[j],
                                                            acc[i][j], 0, 0, 0);
    __syncthreads();
  }
#pragma unroll
  for (int i = 0; i < 4; ++i) {
    int row = bm0 + wr * 64 + i * 16 + fc * 4;
#pragma unroll
    for (int j = 0; j < 4; ++j) {
      int col = bn0 + wc * 64 + j * 16 + fr;
      float bv = bias[col];
#pragma unroll
      for (int q = 0; q < 4; ++q)
        C[(size_t)(row + q) * H_N + col] = f2bf(acc[i][j][q] + bv);
    }
  }
}

// ---------------------------------------------------------------------------
// MFMA bf16 NT GEMM #2: y = hf@Wyf^T + hb@Wyb^T + by, fp32 h converted
// during staging, fp32 output.
// ---------------------------------------------------------------------------
__global__ __launch_bounds__(256) void gemm_out_mfma(
    const float* __restrict__ hf, const float* __restrict__ hb,
    const unsigned short* __restrict__ Wyf, const unsigned short* __restrict__ Wyb,
    const float* __restrict__ by, float* __restrict__ y)
{
  const int bm0 = blockIdx.y * 128;   // T rows
  const int bn0 = blockIdx.x * 128;   // OUT cols

  __shared__ unsigned short As[128 * 40];
  __shared__ unsigned short Bs[128 * 40];

  const int tid  = threadIdx.x;
  const int w    = tid >> 6, lane = tid & 63;
  const int wr   = w >> 1, wc = w & 1;
  const int fr   = lane & 15, fc = lane >> 4;

  f32x4 acc[4][4] = {};

#pragma unroll 1
  for (int pass = 0; pass < 2; ++pass) {
    const float* __restrict__ A = pass ? hb : hf;
    const unsigned short* __restrict__ W = pass ? Wyb : Wyf;
    for (int k0 = 0; k0 < H_N; k0 += 32) {
#pragma unroll
      for (int i = 0; i < 4; ++i) {
        int chunk = tid + i * 256;            // 1024 chunks of 4 f32
        int row = chunk >> 3, c4 = chunk & 7;
        float4 a4 = *(const float4*)(A + (size_t)(bm0 + row) * H_N + k0 + c4 * 4);
        *(ushort4*)(As + row * 40 + c4 * 4) =
            make_ushort4(f2bf(a4.x), f2bf(a4.y), f2bf(a4.z), f2bf(a4.w));
      }
#pragma unroll
      for (int i = 0; i < 2; ++i) {
        int chunk = tid + i * 256;            // 512 chunks of 8 bf16
        int row = chunk >> 2, kk = (chunk & 3) * 8;
        uint4 bv = *(const uint4*)(W + (size_t)(bn0 + row) * H_N + k0 + kk);
        *(uint4*)(Bs + row * 40 + kk) = bv;
      }
      __syncthreads();
      bf16x8 af[4], bfr[4];
#pragma unroll
      for (int i = 0; i < 4; ++i)
        af[i] = *(const bf16x8*)(As + (wr * 64 + i * 16 + fr) * 40 + fc * 8);
#pragma unroll
      for (int j = 0; j < 4; ++j)
        bfr[j] = *(const bf16x8*)(Bs + (wc * 64 + j * 16 + fr) * 40 + fc * 8);
#pragma unroll
      for (int i = 0; i < 4; ++i)
#pragma unroll
        for (int j = 0; j < 4; ++j)
          acc[i][j] = __builtin_amdgcn_mfma_f32_16x16x32_bf16(af[i], bfr[j],
                                                              acc[i][j], 0, 0, 0);
      __syncthreads();
    }
  }
#pragma unroll
  for (int i = 0; i < 4; ++i) {
    int row = bm0 + wr * 64 + i * 16 + fc * 4;
#pragma unroll
    for (int j = 0; j < 4; ++j) {
      int col = bn0 + wc * 64 + j * 16 + fr;
      float bv = by[col];
#pragma unroll
      for (int q = 0; q < 4; ++q)
        y[(size_t)(row + q) * OUT_N + col] = acc[i][j][q] + bv;
    }
  }
}

// ---------------------------------------------------------------------------
// Persistent bidirectional recurrence — EXACT v5 fenceless core; only change:
// xw is bf16 (lane0 reads one 4B word = 2 bf16 and converts).
// ---------------------------------------------------------------------------
__global__ __launch_bounds__(RTH3, 4) void recurrent_kernel(
    const float* __restrict__ Whf, const float* __restrict__ Whb,
    const unsigned short* __restrict__ xwf, const unsigned short* __restrict__ xwb,
    float* __restrict__ hf, float* __restrict__ hb,
    unsigned* __restrict__ progf, unsigned* __restrict__ progb)
{
  const int b    = blockIdx.x;
  const bool fwd = (b < KD3);
  const int bb   = fwd ? b : b - KD3;
  const int rb   = bb * RPB3;
  const float* __restrict__ Wh = fwd ? Whf : Whb;
  const unsigned short* __restrict__ xw = fwd ? xwf : xwb;
  float* __restrict__ hist     = fwd ? hf : hb;
  unsigned* __restrict__ prog  = fwd ? progf : progb;

  const int w     = threadIdx.x >> 6;   // wave 0..15
  const int lane  = threadIdx.x & 63;
  const int jbase = lane << 2;          // 0..252
  const int r0    = rb + 2 * w;         // this wave's two rows

  __shared__ __align__(16) float hs[H_N];   // 8 KB staged h_prev

  float4 wv[2][8];
#pragma unroll
  for (int q = 0; q < 2; ++q)
#pragma unroll
    for (int k = 0; k < 8; ++k)
      wv[q][k] = *(const float4*)(Wh + (size_t)(r0 + q) * H_N + k * 256 + jbase);
#pragma unroll
  for (int q = 0; q < 2; ++q)
#pragma unroll
    for (int k = 0; k < 8; ++k)
      asm volatile("" : "+v"(wv[q][k].x), "+v"(wv[q][k].y),
                        "+v"(wv[q][k].z), "+v"(wv[q][k].w));

  for (int s = 0; s < T_N; ++s) {
    const int t  = fwd ? s : (T_N - 1 - s);
    const int pt = fwd ? (t - 1) : (t + 1);

    // xw prefetch for our two rows (bf16 pair; overlaps the poll).
    float xwv0 = 0.f, xwv1 = 0.f;
    if (lane == 0) {
      unsigned xq = *(const unsigned*)(xw + (size_t)t * H_N + r0);
      xwv0 = bf2f((unsigned short)xq);
      xwv1 = bf2f((unsigned short)(xq >> 16));
    }

    if (s > 0) {
      if (w == 0) {
        for (;;) {
          unsigned p = __hip_atomic_load(prog + lane, __ATOMIC_RELAXED,
                                         __HIP_MEMORY_SCOPE_AGENT);
          if (__all(p >= (unsigned)s)) break;
          __builtin_amdgcn_s_sleep(1);
        }
        asm volatile("" ::: "memory");   // compiler barrier only — no HW fence
      }
      __syncthreads();
      unsigned long long hv2 = __hip_atomic_load(
          (const unsigned long long*)(hist + (size_t)pt * H_N) + threadIdx.x,
          __ATOMIC_RELAXED, __HIP_MEMORY_SCOPE_AGENT);
      *((unsigned long long*)hs + threadIdx.x) = hv2;
      __syncthreads();
    } else {
      *((unsigned long long*)hs + threadIdx.x) = 0ull;
      __syncthreads();
    }

    float acc0 = 0.f, acc1 = 0.f;
#pragma unroll
    for (int k = 0; k < 8; ++k) {
      float4 h4 = *(const float4*)(hs + k * 256 + jbase);
      acc0 = fmaf(wv[0][k].x, h4.x, acc0);
      acc0 = fmaf(wv[0][k].y, h4.y, acc0);
      acc0 = fmaf(wv[0][k].z, h4.z, acc0);
      acc0 = fmaf(wv[0][k].w, h4.w, acc0);
      acc1 = fmaf(wv[1][k].x, h4.x, acc1);
      acc1 = fmaf(wv[1][k].y, h4.y, acc1);
      acc1 = fmaf(wv[1][k].z, h4.z, acc1);
      acc1 = fmaf(wv[1][k].w, h4.w, acc1);
    }
#pragma unroll
    for (int off = 32; off > 0; off >>= 1) {
      acc0 += __shfl_xor(acc0, off, 64);
      acc1 += __shfl_xor(acc1, off, 64);
    }

    if (lane == 0) {
      union { float f; unsigned u; } h0, h1;
      h0.f = tanhf(acc0 + xwv0);
      h1.f = tanhf(acc1 + xwv1);
      unsigned* hu = (unsigned*)(hist + (size_t)t * H_N + r0);
      __hip_atomic_store(hu + 0, h0.u, __ATOMIC_RELAXED, __HIP_MEMORY_SCOPE_AGENT);
      __hip_atomic_store(hu + 1, h1.u, __ATOMIC_RELAXED, __HIP_MEMORY_SCOPE_AGENT);
    }

    __syncthreads();   // per-wave vmcnt drain: stores ACKed at LLC
    if (threadIdx.x == 0)
      __hip_atomic_store(prog + bb, (unsigned)(s + 1), __ATOMIC_RELAXED,
                         __HIP_MEMORY_SCOPE_AGENT);
  }
}

extern "C" void kernel_launch(void* const* d_in, const int* in_sizes, int n_in,
                              void* d_out, int out_size, void* d_ws, size_t ws_size,
                              hipStream_t stream) {
  const float* x   = (const float*)d_in[0];
  const float* Wxf = (const float*)d_in[1];
  const float* Whf = (const float*)d_in[2];
  const float* bhf = (const float*)d_in[3];
  const float* Wxb = (const float*)d_in[4];
  const float* Whb = (const float*)d_in[5];
  const float* bhb = (const float*)d_in[6];
  const float* Wyf = (const float*)d_in[7];
  const float* Wyb = (const float*)d_in[8];
  const float* by  = (const float*)d_in[9];
  float* y = (float*)d_out;

  char* ws = (char*)d_ws;
  unsigned short* xwf = (unsigned short*)(ws + XW_F_OFF);
  unsigned short* xwb = (unsigned short*)(ws + XW_B_OFF);
  float* hf  = (float*)(ws + HF_OFF);
  float* hb  = (float*)(ws + HB_OFF);
  unsigned short* xbf   = (unsigned short*)(ws + XBF_OFF);
  unsigned short* wxfb  = (unsigned short*)(ws + WXF_OFF);
  unsigned short* wxbb  = (unsigned short*)(ws + WXB_OFF);
  unsigned short* wyfb  = (unsigned short*)(ws + WYF_OFF);
  unsigned short* wybb  = (unsigned short*)(ws + WYB_OFF);
  unsigned* progf = (unsigned*)(ws + PROG_OFF);
  unsigned* progb = progf + 64;

  hipLaunchKernelGGL(init_prog_kernel, dim3(1), dim3(128), 0, stream, progf);
  // fp32 -> bf16 conversions
  hipLaunchKernelGGL(cvt_kernel, dim3(1024), dim3(256), 0, stream,
                     (const float4*)x,   (ushort4*)xbf,  (T_N * IN_N) / 4);
  hipLaunchKernelGGL(cvt_kernel, dim3(512), dim3(256), 0, stream,
                     (const float4*)Wxf, (ushort4*)wxfb, (H_N * IN_N) / 4);
  hipLaunchKernelGGL(cvt_kernel, dim3(512), dim3(256), 0, stream,
                     (const float4*)Wxb, (ushort4*)wxbb, (H_N * IN_N) / 4);
  hipLaunchKernelGGL(cvt_kernel, dim3(512), dim3(256), 0, stream,
                     (const float4*)Wyf, (ushort4*)wyfb, (OUT_N * H_N) / 4);
  hipLaunchKernelGGL(cvt_kernel, dim3(512), dim3(256), 0, stream,
                     (const float4*)Wyb, (ushort4*)wybb, (OUT_N * H_N) / 4);

  hipLaunchKernelGGL(gemm_xw_mfma, dim3(H_N / 128, T_N / 128, 2), dim3(256), 0, stream,
                     xbf, wxfb, bhf, wxbb, bhb, xwf, xwb);
  hipLaunchKernelGGL(recurrent_kernel, dim3(2 * KD3), dim3(RTH3), 0, stream,
                     Whf, Whb, xwf, xwb, hf, hb, progf, progb);
  hipLaunchKernelGGL(gemm_out_mfma, dim3(OUT_N / 128, T_N / 128), dim3(256), 0, stream,
                     hf, hb, wyfb, wybb, by, y);
}